// Round 15
// baseline (1503.319 us; speedup 1.0000x reference)
//
#include <hip/hip_runtime.h>
#include <cstdint>

#define LEAK 0.2f

typedef __attribute__((ext_vector_type(8))) short bf16x8;
typedef __attribute__((ext_vector_type(4))) float f32x4;

__device__ __forceinline__ float leaky(float v){ return v >= 0.f ? v : LEAK*v; }

__device__ __forceinline__ uint32_t f32_to_bf16_rne(float v){
    uint32_t u = __float_as_uint(v);
    return (u + 0x7fffu + ((u >> 16) & 1u)) >> 16;
}
// split f32 into (hi,lo) bf16 pair packed hi | lo<<16
__device__ __forceinline__ uint32_t split_pack(float v){
    uint32_t u = __float_as_uint(v);
    uint32_t hb = (u + 0x7fffu + ((u >> 16) & 1u)) & 0xffff0000u;
    float lof = v - __uint_as_float(hb);
    uint32_t lo = f32_to_bf16_rne(lof);
    return (hb >> 16) | (lo << 16);
}

// ---------------------------------------------------------------------------
// Merged style kernel: all 6 layers in ONE launch (grid 48 = 6 layers x 8 b).
// ---------------------------------------------------------------------------
__global__ __launch_bounds__(128)
void style_all_kernel(const float* __restrict__ w,
    const float* __restrict__ m1_w,  const float* __restrict__ m1_b,
    const float* __restrict__ ln1_g, const float* __restrict__ ln1_b,
    const float* __restrict__ a1_sw, const float* __restrict__ a1_sb,
    const float* __restrict__ a1_bw, const float* __restrict__ a1_bb,
    const float* __restrict__ sc1,
    const float* __restrict__ m25_w,  const float* __restrict__ m25_b,
    const float* __restrict__ ln25_g, const float* __restrict__ ln25_b,
    const float* __restrict__ a25_sw, const float* __restrict__ a25_sb,
    const float* __restrict__ a25_bw, const float* __restrict__ a25_bb,
    const float* __restrict__ sc25,
    const float* __restrict__ mr_w,  const float* __restrict__ mr_b,
    const float* __restrict__ lnr_g, const float* __restrict__ lnr_b,
    const float* __restrict__ ar_sw, const float* __restrict__ ar_sb,
    const float* __restrict__ ar_bw, const float* __restrict__ ar_bb,
    const float* __restrict__ scr,
    float* __restrict__ sty)
{
    int l = blockIdx.x >> 3;
    int b = blockIdx.x & 7;
    const float *mw, *mb, *lng, *lnb, *asw, *asb, *abw, *abb, *sc;
    int Cin;
    if (l == 0) {
        mw=m1_w; mb=m1_b; lng=ln1_g; lnb=ln1_b;
        asw=a1_sw; asb=a1_sb; abw=a1_bw; abb=a1_bb; sc=sc1; Cin=128;
    } else if (l <= 4) {
        int j = l - 1;
        mw=m25_w+(size_t)j*32768; mb=m25_b+j*64; lng=ln25_g+j*64; lnb=ln25_b+j*64;
        asw=a25_sw+(size_t)j*32768; asb=a25_sb+j*64;
        abw=a25_bw+(size_t)j*32768; abb=a25_bb+j*64; sc=sc25+j*64; Cin=64;
    } else {
        mw=mr_w; mb=mr_b; lng=lnr_g; lnb=lnr_b;
        asw=ar_sw; asb=ar_sb; abw=ar_bw; abb=ar_bb; sc=scr; Cin=64;
    }
    float* out_sm  = sty + l*3072;
    float* out_asc = out_sm + 1024;
    float* out_abi = out_sm + 2048;

    __shared__ float wl[512];
    __shared__ float red[128];
    int tid = threadIdx.x;
    for (int j = tid; j < 512; j += 128) wl[j] = w[b*512 + j];
    __syncthreads();

    float t = 0.f, ascv = 0.f, abiv = 0.f;
    if (tid < Cin) {
        const float* r1 = mw  + (size_t)tid*512;
        const float* r2 = asw + (size_t)tid*512;
        const float* r3 = abw + (size_t)tid*512;
        for (int j = 0; j < 512; ++j) {
            float wj = wl[j];
            t    = fmaf(wj, r1[j], t);
            ascv = fmaf(wj, r2[j], ascv);
            abiv = fmaf(wj, r3[j], abiv);
        }
        t += mb[tid]; ascv += asb[tid]; abiv += abb[tid];
    }
    red[tid] = (tid < Cin) ? t : 0.f;
    __syncthreads();
    for (int s = 64; s > 0; s >>= 1) { if (tid < s) red[tid] += red[tid+s]; __syncthreads(); }
    float mu = red[0] / (float)Cin;
    __syncthreads();
    float dv = (tid < Cin) ? (t - mu) : 0.f;
    red[tid] = dv*dv;
    __syncthreads();
    for (int s = 64; s > 0; s >>= 1) { if (tid < s) red[tid] += red[tid+s]; __syncthreads(); }
    float var = red[0] / (float)Cin;
    float rstd = rsqrtf(var + 1e-5f);
    if (tid < Cin) {
        float sln = (t - mu) * rstd * lng[tid] + lnb[tid];
        sln = leaky(sln);
        out_sm[b*128 + tid]  = sln * sc[tid];
        out_asc[b*128 + tid] = ascv;
        out_abi[b*128 + tid] = abiv;
    }
}

// ---------------------------------------------------------------------------
// Upsample 2x bilinear -> split-bf16 pair tensor [b][cg(8)][y][x][16c] (u32)
// ---------------------------------------------------------------------------
__global__ __launch_bounds__(256)
void upsample_pack_kernel(const float* __restrict__ x, uint32_t* __restrict__ Up,
                          float* __restrict__ sums)
{
    int bid = blockIdx.x;
    int b = bid >> 8, y = bid & 255;
    int tid = threadIdx.x;
    int c = tid & 15, pg = tid >> 4;
    int q = y >> 1; int rlo, rhi; float wlo, whi;
    if (y & 1) { rlo = q; rhi = (q+1 < 127) ? q+1 : 127; wlo = 0.75f; whi = 0.25f; }
    else       { rlo = (q-1 > 0) ? q-1 : 0; rhi = q;     wlo = 0.25f; whi = 0.75f; }
    __shared__ float xs[2][16][129];
    __shared__ float red2[2][4][16];
    for (int cg = 0; cg < 8; ++cg) {
        __syncthreads();
        for (int e = tid; e < 4096; e += 256) {
            int row = e >> 11, cc = (e >> 7) & 15, px = e & 127;
            xs[row][cc][px] = x[((size_t)(b*128 + cg*16 + cc) << 14) + (row ? rhi : rlo)*128 + px];
        }
        __syncthreads();
        float s = 0.f, sq = 0.f;
        uint32_t* base = Up + ((((size_t)(b*8 + cg)*256 + y)*256))*16 + c;
        #pragma unroll
        for (int k = 0; k < 16; ++k) {
            int px = pg*16 + k;
            int m = px >> 1;
            float v;
            if (px & 1) {
                int m2 = (m+1 < 127) ? m+1 : 127;
                float vc = wlo*xs[0][c][m]  + whi*xs[1][c][m];
                float vr = wlo*xs[0][c][m2] + whi*xs[1][c][m2];
                v = 0.75f*vc + 0.25f*vr;
            } else {
                int m0 = (m-1 > 0) ? m-1 : 0;
                float vl = wlo*xs[0][c][m0] + whi*xs[1][c][m0];
                float vc = wlo*xs[0][c][m]  + whi*xs[1][c][m];
                v = 0.25f*vl + 0.75f*vc;
            }
            s += v; sq += v*v;
            base[(size_t)px*16] = split_pack(v);
        }
        s  += __shfl_xor(s, 16);  s  += __shfl_xor(s, 32);
        sq += __shfl_xor(sq, 16); sq += __shfl_xor(sq, 32);
        int wid = tid >> 6;
        if ((tid & 63) < 16) { red2[0][wid][c] = s; red2[1][wid][c] = sq; }
        __syncthreads();
        if (tid < 16) {
            float S = red2[0][0][tid] + red2[0][1][tid] + red2[0][2][tid] + red2[0][3][tid];
            float Q = red2[1][0][tid] + red2[1][1][tid] + red2[1][2][tid] + red2[1][3][tid];
            atomicAdd(&sums[(b*128 + cg*16 + tid)*2],     S);
            atomicAdd(&sums[(b*128 + cg*16 + tid)*2 + 1], Q);
        }
    }
}

// ---------------------------------------------------------------------------
// Pack skip 1x1 weights, layout [ic][oq][cg][l][8] u16 (wave-contiguous).
// ---------------------------------------------------------------------------
__global__ __launch_bounds__(256)
void packskip_kernel(const float* __restrict__ skw, uint16_t* __restrict__ skp)
{
    int e = blockIdx.x*256 + threadIdx.x;
    if (e >= 8192) return;
    int o = e >> 7, i = e & 127;
    uint32_t pk = split_pack(skw[e]);
    int ic = i >> 4, cl = i & 15, cg = cl >> 2, j2 = (cl & 3)*2;
    uint16_t* dst = skp + ic*2048 + (o >> 4)*512 + cg*128 + (o & 15)*8 + j2;
    dst[0] = (uint16_t)(pk & 0xffffu);
    dst[1] = (uint16_t)(pk >> 16);
}

// ---------------------------------------------------------------------------
// packW: layout per ic-chunk [tap][oq(4)][cg(4)][l(16)][16B] (wave-contiguous)
// r15: demod FUSED here (dmod = rsqrt(sum_i,k (c9*sm)^2 + 1e-8)) — the old
// demod_kernel launch is deleted.
// ---------------------------------------------------------------------------
template<int CIN>
__global__ __launch_bounds__(CIN)
void packw_kernel(const float* __restrict__ wt, const float* __restrict__ sty,
                  const float* __restrict__ sums,
                  uint16_t* __restrict__ wp, float* __restrict__ bias9,
                  float* __restrict__ dmodL)
{
    int b = blockIdx.x >> 6;
    int o = blockIdx.x & 63;
    int i = threadIdx.x;

    float sm = sty[b*128 + i];
    float av = sty[1024 + b*128 + i];
    float bv = sty[2048 + b*128 + i];
    float s0 = sums[(b*CIN + i)*2], s1 = sums[(b*CIN + i)*2 + 1];
    float m = s0 * (1.f/65536.f);
    float var = s1 * (1.f/65536.f) - m*m;
    float r = rsqrtf((var > 0.f ? var : 0.f) + 1e-5f);
    float A  = sm * av * r;
    float Bv = sm * (bv - av*m*r);

    const float* wrow = wt + ((size_t)o*CIN + i)*9;
    float c9[9];
    #pragma unroll
    for (int k = 0; k < 9; ++k) c9[k] = wrow[k];

    const int NCH = CIN/16;
    int ic = i >> 4, cl = i & 15, cg = cl >> 2, j2 = (cl & 3)*2;
    uint16_t* wpb = wp + ((size_t)b*NCH + ic)*18432;
    float wsq = 0.f;
    #pragma unroll
    for (int k = 0; k < 9; ++k) { wsq = fmaf(c9[k], c9[k], wsq); }
    #pragma unroll
    for (int k = 0; k < 9; ++k) {
        float wv = c9[k] * A;
        uint32_t pk = split_pack(wv);
        uint16_t* dst = wpb + k*2048 + (o >> 4)*512 + cg*128 + (o & 15)*8 + j2;
        dst[0] = (uint16_t)(pk & 0xffffu);
        dst[1] = (uint16_t)(pk >> 16);
    }

    float colS[3][3];
    #pragma unroll
    for (int ky = 0; ky < 3; ++ky) {
        colS[ky][0] = c9[ky*3+1] + c9[ky*3+2];
        colS[ky][1] = c9[ky*3+0] + c9[ky*3+1] + c9[ky*3+2];
        colS[ky][2] = c9[ky*3+0] + c9[ky*3+1];
    }
    float part[9];
    #pragma unroll
    for (int rx = 0; rx < 3; ++rx) {
        part[0*3+rx] = colS[1][rx] + colS[2][rx];
        part[1*3+rx] = colS[0][rx] + colS[1][rx] + colS[2][rx];
        part[2*3+rx] = colS[0][rx] + colS[1][rx];
    }
    __shared__ float red[10][CIN];
    #pragma unroll
    for (int t = 0; t < 9; ++t) red[t][i] = part[t] * Bv;
    red[9][i] = wsq * sm * sm;
    __syncthreads();
    for (int s = CIN/2; s > 0; s >>= 1) {
        if (i < s) {
            #pragma unroll
            for (int t = 0; t < 10; ++t) red[t][i] += red[t][i + s];
        }
        __syncthreads();
    }
    if (i < 9) bias9[((size_t)(b*64 + o))*9 + i] = red[i][0];
    if (i == 9) dmodL[b*64 + o] = rsqrtf(red[9][0] + 1e-8f);
}

// ---------------------------------------------------------------------------
// MFMA conv 3x3 over pair tensors [b][cg][y][x][16c].  (structure = r12 best)
//   MODE 1: out pairs (direct coalesced store) + stats.
//   MODE 2: out f32 (+= skip already in h) + stats.
//   SKIP:   also compute 1x1 skip conv -> f32 skipOut.
// block 512 (8 waves = 2 rows x 4 o-quarters); tile 2 rows x 128 px x 64 oc.
// W fragments read directly from global (L2-resident); LDS holds X only.
// r15: for !SKIP, tap body reordered (load all 8 bf -> 8x wa-MFMA -> 8x
// wb-MFMA) to raise same-acc dependency distance 1 -> 8.  Register math:
// 64 arch + 32 acc + 32 bfv = 128 total (4 waves/SIMD preserved).  SKIP
// variant (conv1, already 128 total) keeps the old ordering.
// ---------------------------------------------------------------------------
template<int CIN, int MODE, bool SKIP>
__global__ __launch_bounds__(512)
void conv_mfma_kernel(const uint32_t* __restrict__ inPair,
                      const uint16_t* __restrict__ Wp,
                      const float* __restrict__ bias9,
                      const float* __restrict__ dmod,
                      const uint16_t* __restrict__ skp,
                      const float* __restrict__ skb,
                      float* __restrict__ skipOut,
                      uint32_t* __restrict__ outPair,
                      float* __restrict__ outF32,
                      float* __restrict__ statsH)
{
    __shared__ __align__(16) unsigned char LDS[41600];
    // X only: [4 rows][130 px], slot 80B, row stride 10400B.
    const int tid = threadIdx.x;
    const int lane = tid & 63, wv = tid >> 6;
    const int rw = wv >> 2, oq = wv & 3;

    int bid = blockIdx.x;
    bid = (bid & 7) * 256 + (bid >> 3);        // XCD-chunked bijective swizzle
    const int xh = bid & 1, yb = (bid >> 1) & 127, b = bid >> 8;
    const int y0 = yb*2, x0 = xh*128;

    union U8 { uint32_t u[4]; bf16x8 v; };

    f32x4 acc[8];
    f32x4 accS[SKIP ? 8 : 1];
    #pragma unroll
    for (int q = 0; q < 8; ++q) acc[q] = (f32x4){0.f, 0.f, 0.f, 0.f};
    if constexpr (SKIP) {
        #pragma unroll
        for (int q = 0; q < 8; ++q) accS[q] = (f32x4){0.f, 0.f, 0.f, 0.f};
    }

    const int NCH = CIN/16;
    for (int ic = 0; ic < NCH; ++ic) {
        // ---- stage X (only LDS use)
        for (int e = tid; e < 2080; e += 512) {
            int part = e & 3;
            int pr = e >> 2;
            int px = pr % 130, row = pr / 130;
            int yy = y0 - 1 + row, xx = x0 - 1 + px;
            uint4 v = {0u, 0u, 0u, 0u};
            if (yy >= 0 && yy < 256 && xx >= 0 && xx < 256)
                v = *reinterpret_cast<const uint4*>(
                    inPair + ((((size_t)b*NCH + ic)*256 + yy)*256 + xx)*16 + part*4);
            *reinterpret_cast<uint4*>(LDS + row*10400 + px*80 + part*16) = v;
        }
        __syncthreads();
        // ---- compute: 9 taps x 8 x-frags x 2 mfma; W from global (L2-hot)
        const uint16_t* wbase = Wp + ((size_t)b*NCH + ic)*18432
                              + oq*512 + (lane >> 4)*128 + (lane & 15)*8;
        #pragma unroll
        for (int tap = 0; tap < 9; ++tap) {
            const int dy1 = tap/3, dxm = tap % 3;
            uint4 wv4 = *reinterpret_cast<const uint4*>(wbase + tap*2048);
            U8 wa, wb;
            #pragma unroll
            for (int q = 0; q < 4; ++q) {
                uint32_t ww = (&wv4.x)[q];
                wa.u[q] = __builtin_amdgcn_perm(ww, ww, 0x01000100u);
                wb.u[q] = __builtin_amdgcn_perm(ww, ww, 0x03020302u);
            }
            const int rowbase = (rw + dy1)*10400 + (lane >> 4)*16 + ((lane & 15) + dxm)*80;
            if constexpr (!SKIP) {
                // r15 reorder: widen same-acc dependency distance to 8
                bf16x8 bfv[8];
                #pragma unroll
                for (int xf = 0; xf < 8; ++xf)
                    bfv[xf] = *reinterpret_cast<const bf16x8*>(LDS + rowbase + xf*1280);
                #pragma unroll
                for (int xf = 0; xf < 8; ++xf)
                    acc[xf] = __builtin_amdgcn_mfma_f32_16x16x32_bf16(wa.v, bfv[xf], acc[xf], 0, 0, 0);
                #pragma unroll
                for (int xf = 0; xf < 8; ++xf)
                    acc[xf] = __builtin_amdgcn_mfma_f32_16x16x32_bf16(wb.v, bfv[xf], acc[xf], 0, 0, 0);
            } else {
                U8 sa, sb;
                if (tap == 4) {
                    uint4 sfrag = *reinterpret_cast<const uint4*>(
                        skp + ic*2048 + oq*512 + (lane >> 4)*128 + (lane & 15)*8);
                    #pragma unroll
                    for (int q = 0; q < 4; ++q) {
                        uint32_t ww = (&sfrag.x)[q];
                        sa.u[q] = __builtin_amdgcn_perm(ww, ww, 0x01000100u);
                        sb.u[q] = __builtin_amdgcn_perm(ww, ww, 0x03020302u);
                    }
                }
                #pragma unroll
                for (int xf = 0; xf < 8; ++xf) {
                    bf16x8 bf = *reinterpret_cast<const bf16x8*>(LDS + rowbase + xf*1280);
                    acc[xf] = __builtin_amdgcn_mfma_f32_16x16x32_bf16(wa.v, bf, acc[xf], 0, 0, 0);
                    acc[xf] = __builtin_amdgcn_mfma_f32_16x16x32_bf16(wb.v, bf, acc[xf], 0, 0, 0);
                    if (tap == 4) {
                        accS[xf] = __builtin_amdgcn_mfma_f32_16x16x32_bf16(sa.v, bf, accS[xf], 0, 0, 0);
                        accS[xf] = __builtin_amdgcn_mfma_f32_16x16x32_bf16(sb.v, bf, accS[xf], 0, 0, 0);
                    }
                }
            }
        }
        __syncthreads();
    }

    // ---- epilogue
    const int y = y0 + rw;
    const int ry = (y == 0) ? 0 : ((y == 255) ? 2 : 1);
    float dv4[4], bmid[4], bl[4], br[4], skb4[4];
    #pragma unroll
    for (int r2 = 0; r2 < 4; ++r2) {
        int o = oq*16 + (lane >> 4)*4 + r2;
        dv4[r2] = dmod[b*64 + o];
        const float* bp = bias9 + ((size_t)(b*64 + o))*9 + ry*3;
        bmid[r2] = bp[1];
        bl[r2] = bmid[r2]; br[r2] = bmid[r2];
        if (x0 == 0   && (lane & 15) == 0)  bl[r2] = bp[0];
        if (x0 == 128 && (lane & 15) == 15) br[r2] = bp[2];
        if constexpr (SKIP) skb4[r2] = skb[o];
    }

    float s4[4] = {0.f,0.f,0.f,0.f}, q4[4] = {0.f,0.f,0.f,0.f};
    #pragma unroll
    for (int xf = 0; xf < 8; ++xf) {
        #pragma unroll
        for (int r2 = 0; r2 < 4; ++r2) {
            float bias = (xf == 0) ? bl[r2] : ((xf == 7) ? br[r2] : bmid[r2]);
            float v = (acc[xf][r2] + bias) * dv4[r2];
            v = leaky(v);
            acc[xf][r2] = v;
            if (MODE != 2) { s4[r2] += v; q4[r2] += v*v; }
        }
    }

    if constexpr (SKIP) {
        #pragma unroll
        for (int xf = 0; xf < 8; ++xf) {
            #pragma unroll
            for (int r2 = 0; r2 < 4; ++r2) {
                int o = oq*16 + (lane >> 4)*4 + r2;
                size_t addr = ((size_t)(b*64 + o))*65536 + (size_t)y*256 + x0 + xf*16 + (lane & 15);
                skipOut[addr] = accS[xf][r2] + skb4[r2];
            }
        }
    }

    if constexpr (MODE == 2) {
        #pragma unroll
        for (int xf = 0; xf < 8; ++xf) {
            #pragma unroll
            for (int r2 = 0; r2 < 4; ++r2) {
                int o = oq*16 + (lane >> 4)*4 + r2;
                size_t addr = ((size_t)(b*64 + o))*65536 + (size_t)y*256 + x0 + xf*16 + (lane & 15);
                float v = acc[xf][r2] + outF32[addr];
                outF32[addr] = v;
                s4[r2] += v; q4[r2] += v*v;
            }
        }
    }

    // stats reduce: 16 lanes share the same o's
    #pragma unroll
    for (int r2 = 0; r2 < 4; ++r2) {
        #pragma unroll
        for (int w = 1; w < 16; w <<= 1) {
            s4[r2] += __shfl_xor(s4[r2], w);
            q4[r2] += __shfl_xor(q4[r2], w);
        }
    }
    if ((lane & 15) == 0) {
        #pragma unroll
        for (int r2 = 0; r2 < 4; ++r2) {
            int o = oq*16 + (lane >> 4)*4 + r2;
            atomicAdd(&statsH[(b*64 + o)*2],     s4[r2]);
            atomicAdd(&statsH[(b*64 + o)*2 + 1], q4[r2]);
        }
    }

    if constexpr (MODE != 2) {
        // direct coalesced pair store (no LDS, no barriers)
        uint32_t* outb = outPair + ((((size_t)b*4 + oq)*256 + y)*256 + x0)*16 + (lane >> 4)*4;
        #pragma unroll
        for (int xf = 0; xf < 8; ++xf) {
            int px = xf*16 + (lane & 15);
            uint4 pk4;
            pk4.x = split_pack(acc[xf][0]);
            pk4.y = split_pack(acc[xf][1]);
            pk4.z = split_pack(acc[xf][2]);
            pk4.w = split_pack(acc[xf][3]);
            *reinterpret_cast<uint4*>(outb + (size_t)px*16) = pk4;
        }
    }
}

// ---------------------------------------------------------------------------
// RGB 1x1 modconv; instance-norm stats derived from fused sums.
// ---------------------------------------------------------------------------
__global__ __launch_bounds__(256)
void rgb_kernel(const float* __restrict__ h, const float* __restrict__ wr,
                const float* __restrict__ sty, const float* __restrict__ sums,
                float* __restrict__ rgb)
{
    __shared__ float A[64], Bc[64];
    __shared__ float wl[192];
    int bid = blockIdx.x;
    int b = bid >> 7;
    int px0 = (bid & 127) * 512;
    int tid = threadIdx.x;
    if (tid < 64) {
        float smv = sty[b*128 + tid];
        float av  = sty[1024 + b*128 + tid];
        float bv  = sty[2048 + b*128 + tid];
        float s0 = sums[(b*64 + tid)*2], s1 = sums[(b*64 + tid)*2 + 1];
        float m = s0 * (1.f/65536.f);
        float var = s1 * (1.f/65536.f) - m*m;
        float r = rsqrtf((var > 0.f ? var : 0.f) + 1e-5f);
        A[tid]  = smv * av * r;
        Bc[tid] = smv * (bv - av*m*r);
    }
    if (tid < 192) wl[tid] = wr[tid];
    __syncthreads();
    int pix = px0 + tid*2;
    const float* hp = h + (size_t)b*64*65536 + pix;
    float a0[3] = {0,0,0}, a1[3] = {0,0,0};
    for (int i = 0; i < 64; ++i) {
        float2 v = *reinterpret_cast<const float2*>(hp + (size_t)i*65536);
        float xi0 = fmaf(A[i], v.x, Bc[i]);
        float xi1 = fmaf(A[i], v.y, Bc[i]);
        #pragma unroll
        for (int o = 0; o < 3; ++o) {
            float wv = wl[o*64 + i];
            a0[o] = fmaf(wv, xi0, a0[o]);
            a1[o] = fmaf(wv, xi1, a1[o]);
        }
    }
    float* rp = rgb + (size_t)b*3*65536 + pix;
    #pragma unroll
    for (int o = 0; o < 3; ++o)
        *reinterpret_cast<float2*>(rp + (size_t)o*65536) = make_float2(a0[o], a1[o]);
}

// ---------------------------------------------------------------------------
extern "C" void kernel_launch(void* const* d_in, const int* in_sizes, int n_in,
                              void* d_out, int out_size, void* d_ws, size_t ws_size,
                              hipStream_t stream)
{
    const float* x     = (const float*)d_in[0];
    const float* w     = (const float*)d_in[1];
    const float* w1    = (const float*)d_in[2];
    const float* sc1   = (const float*)d_in[3];
    const float* m1_w  = (const float*)d_in[4];
    const float* m1_b  = (const float*)d_in[5];
    const float* ln1_g = (const float*)d_in[6];
    const float* ln1_b = (const float*)d_in[7];
    const float* a1_sw = (const float*)d_in[8];
    const float* a1_sb = (const float*)d_in[9];
    const float* a1_bw = (const float*)d_in[10];
    const float* a1_bb = (const float*)d_in[11];
    const float* w25   = (const float*)d_in[12];
    const float* sc25  = (const float*)d_in[13];
    const float* m25_w = (const float*)d_in[14];
    const float* m25_b = (const float*)d_in[15];
    const float* ln25_g= (const float*)d_in[16];
    const float* ln25_b= (const float*)d_in[17];
    const float* a25_sw= (const float*)d_in[18];
    const float* a25_sb= (const float*)d_in[19];
    const float* a25_bw= (const float*)d_in[20];
    const float* a25_bb= (const float*)d_in[21];
    const float* wr    = (const float*)d_in[22];
    const float* scr   = (const float*)d_in[23];
    const float* mr_w  = (const float*)d_in[24];
    const float* mr_b  = (const float*)d_in[25];
    const float* lnr_g = (const float*)d_in[26];
    const float* lnr_b = (const float*)d_in[27];
    const float* ar_sw = (const float*)d_in[28];
    const float* ar_sb = (const float*)d_in[29];
    const float* ar_bw = (const float*)d_in[30];
    const float* ar_bb = (const float*)d_in[31];
    const float* sk_w  = (const float*)d_in[32];
    const float* sk_b  = (const float*)d_in[33];

    float* outp    = (float*)d_out;
    float* h_out   = outp;                        // [8,64,256,256] f32
    float* rgb_out = outp + (size_t)33554432;     // [8,3,256,256]  f32

    uint8_t* ws = (uint8_t*)d_ws;
    uint32_t*  Upair  = (uint32_t*)(ws + 0);
    uint32_t*  hpB    = (uint32_t*)(ws + 0);
    uint32_t*  hpA    = (uint32_t*)(ws + 268435456ull);
    uint16_t*  WpBase = (uint16_t*)(ws + 402653184ull);
    float*     sty    = (float*)(ws + 409731072ull);
    float*     dmod   = (float*)(ws + 409804800ull);
    float*     stats  = (float*)(ws + 409815040ull);
    float*     bias9  = (float*)(ws + 409843712ull);
    uint16_t*  skp    = (uint16_t*)(ws + 409935872ull);

    float* sumsU = stats;
    float* st1   = stats + 2048;
    float* st2   = stats + 3072;
    float* st3   = stats + 4096;
    float* st4   = stats + 5120;
    float* st5   = stats + 6144;

    uint16_t* Wp1 = WpBase;
    uint16_t* Wp2 = WpBase + 1179648;
    uint16_t* Wp3 = Wp2 + 589824;
    uint16_t* Wp4 = Wp3 + 589824;
    uint16_t* Wp5 = Wp4 + 589824;

    hipMemsetAsync(stats, 0, 28672, stream);

    // 1. styles: single merged launch (6 layers x 8 batches concurrent)
    style_all_kernel<<<48,128,0,stream>>>(w,
        m1_w, m1_b, ln1_g, ln1_b, a1_sw, a1_sb, a1_bw, a1_bb, sc1,
        m25_w, m25_b, ln25_g, ln25_b, a25_sw, a25_sb, a25_bw, a25_bb, sc25,
        mr_w, mr_b, lnr_g, lnr_b, ar_sw, ar_sb, ar_bw, ar_bb, scr,
        sty);

    // 2. skip-weight pack (demod now fused into packw)
    packskip_kernel<<<32,256,0,stream>>>(sk_w, skp);

    // 3. upsample -> pair tensor + sums
    upsample_pack_kernel<<<2048,256,0,stream>>>(x, Upair, sumsU);

    // 4. conv1 (128->64) with fused skip -> hpA pairs + h_out (skip f32)
    packw_kernel<128><<<512,128,0,stream>>>(w1, sty, sumsU, Wp1, bias9, dmod);
    conv_mfma_kernel<128,1,true><<<2048,512,0,stream>>>(Upair, Wp1, bias9, dmod,
                                                        skp, sk_b, h_out,
                                                        hpA, nullptr, st1);
    // 5. conv2..conv4
    packw_kernel<64><<<512,64,0,stream>>>(w25, sty + 3072, st1, Wp2, bias9 + 4608, dmod + 512);
    conv_mfma_kernel<64,1,false><<<2048,512,0,stream>>>(hpA, Wp2, bias9 + 4608, dmod + 512,
                                                        nullptr, nullptr, nullptr,
                                                        hpB, nullptr, st2);
    packw_kernel<64><<<512,64,0,stream>>>(w25 + 36864, sty + 2*3072, st2, Wp3, bias9 + 2*4608, dmod + 2*512);
    conv_mfma_kernel<64,1,false><<<2048,512,0,stream>>>(hpB, Wp3, bias9 + 2*4608, dmod + 2*512,
                                                        nullptr, nullptr, nullptr,
                                                        hpA, nullptr, st3);
    packw_kernel<64><<<512,64,0,stream>>>(w25 + 2*36864, sty + 3*3072, st3, Wp4, bias9 + 3*4608, dmod + 3*512);
    conv_mfma_kernel<64,1,false><<<2048,512,0,stream>>>(hpA, Wp4, bias9 + 3*4608, dmod + 3*512,
                                                        nullptr, nullptr, nullptr,
                                                        hpB, nullptr, st4);
    // 6. conv5 + skip add -> d_out.h (f32), h stats fused
    packw_kernel<64><<<512,64,0,stream>>>(w25 + 3*36864, sty + 4*3072, st4, Wp5, bias9 + 4*4608, dmod + 4*512);
    conv_mfma_kernel<64,2,false><<<2048,512,0,stream>>>(hpB, Wp5, bias9 + 4*4608, dmod + 4*512,
                                                        nullptr, nullptr, nullptr,
                                                        nullptr, h_out, st5);

    // 7. rgb head
    rgb_kernel<<<1024,256,0,stream>>>(h_out, wr, sty + 5*3072, st5, rgb_out);
}

// Round 16
// 1322.393 us; speedup vs baseline: 1.1368x; 1.1368x over previous
//
#include <hip/hip_runtime.h>
#include <cstdint>

#define LEAK 0.2f

typedef __attribute__((ext_vector_type(8))) short bf16x8;
typedef __attribute__((ext_vector_type(4))) float f32x4;

__device__ __forceinline__ float leaky(float v){ return v >= 0.f ? v : LEAK*v; }

__device__ __forceinline__ uint32_t f32_to_bf16_rne(float v){
    uint32_t u = __float_as_uint(v);
    return (u + 0x7fffu + ((u >> 16) & 1u)) >> 16;
}
// split f32 into (hi,lo) bf16 pair packed hi | lo<<16
__device__ __forceinline__ uint32_t split_pack(float v){
    uint32_t u = __float_as_uint(v);
    uint32_t hb = (u + 0x7fffu + ((u >> 16) & 1u)) & 0xffff0000u;
    float lof = v - __uint_as_float(hb);
    uint32_t lo = f32_to_bf16_rne(lof);
    return (hb >> 16) | (lo << 16);
}

// ---------------------------------------------------------------------------
// Merged style kernel: all 6 layers in ONE launch (grid 48 = 6 layers x 8 b).
// ---------------------------------------------------------------------------
__global__ __launch_bounds__(128)
void style_all_kernel(const float* __restrict__ w,
    const float* __restrict__ m1_w,  const float* __restrict__ m1_b,
    const float* __restrict__ ln1_g, const float* __restrict__ ln1_b,
    const float* __restrict__ a1_sw, const float* __restrict__ a1_sb,
    const float* __restrict__ a1_bw, const float* __restrict__ a1_bb,
    const float* __restrict__ sc1,
    const float* __restrict__ m25_w,  const float* __restrict__ m25_b,
    const float* __restrict__ ln25_g, const float* __restrict__ ln25_b,
    const float* __restrict__ a25_sw, const float* __restrict__ a25_sb,
    const float* __restrict__ a25_bw, const float* __restrict__ a25_bb,
    const float* __restrict__ sc25,
    const float* __restrict__ mr_w,  const float* __restrict__ mr_b,
    const float* __restrict__ lnr_g, const float* __restrict__ lnr_b,
    const float* __restrict__ ar_sw, const float* __restrict__ ar_sb,
    const float* __restrict__ ar_bw, const float* __restrict__ ar_bb,
    const float* __restrict__ scr,
    float* __restrict__ sty)
{
    int l = blockIdx.x >> 3;
    int b = blockIdx.x & 7;
    const float *mw, *mb, *lng, *lnb, *asw, *asb, *abw, *abb, *sc;
    int Cin;
    if (l == 0) {
        mw=m1_w; mb=m1_b; lng=ln1_g; lnb=ln1_b;
        asw=a1_sw; asb=a1_sb; abw=a1_bw; abb=a1_bb; sc=sc1; Cin=128;
    } else if (l <= 4) {
        int j = l - 1;
        mw=m25_w+(size_t)j*32768; mb=m25_b+j*64; lng=ln25_g+j*64; lnb=ln25_b+j*64;
        asw=a25_sw+(size_t)j*32768; asb=a25_sb+j*64;
        abw=a25_bw+(size_t)j*32768; abb=a25_bb+j*64; sc=sc25+j*64; Cin=64;
    } else {
        mw=mr_w; mb=mr_b; lng=lnr_g; lnb=lnr_b;
        asw=ar_sw; asb=ar_sb; abw=ar_bw; abb=ar_bb; sc=scr; Cin=64;
    }
    float* out_sm  = sty + l*3072;
    float* out_asc = out_sm + 1024;
    float* out_abi = out_sm + 2048;

    __shared__ float wl[512];
    __shared__ float red[128];
    int tid = threadIdx.x;
    for (int j = tid; j < 512; j += 128) wl[j] = w[b*512 + j];
    __syncthreads();

    float t = 0.f, ascv = 0.f, abiv = 0.f;
    if (tid < Cin) {
        const float* r1 = mw  + (size_t)tid*512;
        const float* r2 = asw + (size_t)tid*512;
        const float* r3 = abw + (size_t)tid*512;
        for (int j = 0; j < 512; ++j) {
            float wj = wl[j];
            t    = fmaf(wj, r1[j], t);
            ascv = fmaf(wj, r2[j], ascv);
            abiv = fmaf(wj, r3[j], abiv);
        }
        t += mb[tid]; ascv += asb[tid]; abiv += abb[tid];
    }
    red[tid] = (tid < Cin) ? t : 0.f;
    __syncthreads();
    for (int s = 64; s > 0; s >>= 1) { if (tid < s) red[tid] += red[tid+s]; __syncthreads(); }
    float mu = red[0] / (float)Cin;
    __syncthreads();
    float dv = (tid < Cin) ? (t - mu) : 0.f;
    red[tid] = dv*dv;
    __syncthreads();
    for (int s = 64; s > 0; s >>= 1) { if (tid < s) red[tid] += red[tid+s]; __syncthreads(); }
    float var = red[0] / (float)Cin;
    float rstd = rsqrtf(var + 1e-5f);
    if (tid < Cin) {
        float sln = (t - mu) * rstd * lng[tid] + lnb[tid];
        sln = leaky(sln);
        out_sm[b*128 + tid]  = sln * sc[tid];
        out_asc[b*128 + tid] = ascv;
        out_abi[b*128 + tid] = abiv;
    }
}

// ---------------------------------------------------------------------------
// Upsample 2x bilinear -> split-bf16 pair tensor [b][cg(8)][y][x][16c] (u32)
// ---------------------------------------------------------------------------
__global__ __launch_bounds__(256)
void upsample_pack_kernel(const float* __restrict__ x, uint32_t* __restrict__ Up,
                          float* __restrict__ sums)
{
    int bid = blockIdx.x;
    int b = bid >> 8, y = bid & 255;
    int tid = threadIdx.x;
    int c = tid & 15, pg = tid >> 4;
    int q = y >> 1; int rlo, rhi; float wlo, whi;
    if (y & 1) { rlo = q; rhi = (q+1 < 127) ? q+1 : 127; wlo = 0.75f; whi = 0.25f; }
    else       { rlo = (q-1 > 0) ? q-1 : 0; rhi = q;     wlo = 0.25f; whi = 0.75f; }
    __shared__ float xs[2][16][129];
    __shared__ float red2[2][4][16];
    for (int cg = 0; cg < 8; ++cg) {
        __syncthreads();
        for (int e = tid; e < 4096; e += 256) {
            int row = e >> 11, cc = (e >> 7) & 15, px = e & 127;
            xs[row][cc][px] = x[((size_t)(b*128 + cg*16 + cc) << 14) + (row ? rhi : rlo)*128 + px];
        }
        __syncthreads();
        float s = 0.f, sq = 0.f;
        uint32_t* base = Up + ((((size_t)(b*8 + cg)*256 + y)*256))*16 + c;
        #pragma unroll
        for (int k = 0; k < 16; ++k) {
            int px = pg*16 + k;
            int m = px >> 1;
            float v;
            if (px & 1) {
                int m2 = (m+1 < 127) ? m+1 : 127;
                float vc = wlo*xs[0][c][m]  + whi*xs[1][c][m];
                float vr = wlo*xs[0][c][m2] + whi*xs[1][c][m2];
                v = 0.75f*vc + 0.25f*vr;
            } else {
                int m0 = (m-1 > 0) ? m-1 : 0;
                float vl = wlo*xs[0][c][m0] + whi*xs[1][c][m0];
                float vc = wlo*xs[0][c][m]  + whi*xs[1][c][m];
                v = 0.25f*vl + 0.75f*vc;
            }
            s += v; sq += v*v;
            base[(size_t)px*16] = split_pack(v);
        }
        s  += __shfl_xor(s, 16);  s  += __shfl_xor(s, 32);
        sq += __shfl_xor(sq, 16); sq += __shfl_xor(sq, 32);
        int wid = tid >> 6;
        if ((tid & 63) < 16) { red2[0][wid][c] = s; red2[1][wid][c] = sq; }
        __syncthreads();
        if (tid < 16) {
            float S = red2[0][0][tid] + red2[0][1][tid] + red2[0][2][tid] + red2[0][3][tid];
            float Q = red2[1][0][tid] + red2[1][1][tid] + red2[1][2][tid] + red2[1][3][tid];
            atomicAdd(&sums[(b*128 + cg*16 + tid)*2],     S);
            atomicAdd(&sums[(b*128 + cg*16 + tid)*2 + 1], Q);
        }
    }
}

// ---------------------------------------------------------------------------
// Pack skip 1x1 weights, layout [ic][oq][cg][l][8] u16 (wave-contiguous).
// ---------------------------------------------------------------------------
__global__ __launch_bounds__(256)
void packskip_kernel(const float* __restrict__ skw, uint16_t* __restrict__ skp)
{
    int e = blockIdx.x*256 + threadIdx.x;
    if (e >= 8192) return;
    int o = e >> 7, i = e & 127;
    uint32_t pk = split_pack(skw[e]);
    int ic = i >> 4, cl = i & 15, cg = cl >> 2, j2 = (cl & 3)*2;
    uint16_t* dst = skp + ic*2048 + (o >> 4)*512 + cg*128 + (o & 15)*8 + j2;
    dst[0] = (uint16_t)(pk & 0xffffu);
    dst[1] = (uint16_t)(pk >> 16);
}

// ---------------------------------------------------------------------------
// packW: layout per ic-chunk [tap][oq(4)][cg(4)][l(16)][16B] (wave-contiguous)
// demod fused (dmod = rsqrt(sum_i,k (c9*sm)^2 + 1e-8)); no demod launch.
// ---------------------------------------------------------------------------
template<int CIN>
__global__ __launch_bounds__(CIN)
void packw_kernel(const float* __restrict__ wt, const float* __restrict__ sty,
                  const float* __restrict__ sums,
                  uint16_t* __restrict__ wp, float* __restrict__ bias9,
                  float* __restrict__ dmodL)
{
    int b = blockIdx.x >> 6;
    int o = blockIdx.x & 63;
    int i = threadIdx.x;

    float sm = sty[b*128 + i];
    float av = sty[1024 + b*128 + i];
    float bv = sty[2048 + b*128 + i];
    float s0 = sums[(b*CIN + i)*2], s1 = sums[(b*CIN + i)*2 + 1];
    float m = s0 * (1.f/65536.f);
    float var = s1 * (1.f/65536.f) - m*m;
    float r = rsqrtf((var > 0.f ? var : 0.f) + 1e-5f);
    float A  = sm * av * r;
    float Bv = sm * (bv - av*m*r);

    const float* wrow = wt + ((size_t)o*CIN + i)*9;
    float c9[9];
    #pragma unroll
    for (int k = 0; k < 9; ++k) c9[k] = wrow[k];

    const int NCH = CIN/16;
    int ic = i >> 4, cl = i & 15, cg = cl >> 2, j2 = (cl & 3)*2;
    uint16_t* wpb = wp + ((size_t)b*NCH + ic)*18432;
    float wsq = 0.f;
    #pragma unroll
    for (int k = 0; k < 9; ++k) { wsq = fmaf(c9[k], c9[k], wsq); }
    #pragma unroll
    for (int k = 0; k < 9; ++k) {
        float wv = c9[k] * A;
        uint32_t pk = split_pack(wv);
        uint16_t* dst = wpb + k*2048 + (o >> 4)*512 + cg*128 + (o & 15)*8 + j2;
        dst[0] = (uint16_t)(pk & 0xffffu);
        dst[1] = (uint16_t)(pk >> 16);
    }

    float colS[3][3];
    #pragma unroll
    for (int ky = 0; ky < 3; ++ky) {
        colS[ky][0] = c9[ky*3+1] + c9[ky*3+2];
        colS[ky][1] = c9[ky*3+0] + c9[ky*3+1] + c9[ky*3+2];
        colS[ky][2] = c9[ky*3+0] + c9[ky*3+1];
    }
    float part[9];
    #pragma unroll
    for (int rx = 0; rx < 3; ++rx) {
        part[0*3+rx] = colS[1][rx] + colS[2][rx];
        part[1*3+rx] = colS[0][rx] + colS[1][rx] + colS[2][rx];
        part[2*3+rx] = colS[0][rx] + colS[1][rx];
    }
    __shared__ float red[10][CIN];
    #pragma unroll
    for (int t = 0; t < 9; ++t) red[t][i] = part[t] * Bv;
    red[9][i] = wsq * sm * sm;
    __syncthreads();
    for (int s = CIN/2; s > 0; s >>= 1) {
        if (i < s) {
            #pragma unroll
            for (int t = 0; t < 10; ++t) red[t][i] += red[t][i + s];
        }
        __syncthreads();
    }
    if (i < 9) bias9[((size_t)(b*64 + o))*9 + i] = red[i][0];
    if (i == 9) dmodL[b*64 + o] = rsqrtf(red[9][0] + 1e-8f);
}

// ---------------------------------------------------------------------------
// MFMA conv 3x3 over pair tensors [b][cg][y][x][16c].  (r12/r14 exact — best)
//   MODE 1: out pairs (direct coalesced store) + stats.
//   MODE 2: out f32 (+= skip already in h) + stats.
//   SKIP:   also compute 1x1 skip conv -> f32 skipOut.
// block 512 (8 waves = 2 rows x 4 o-quarters); tile 2 rows x 128 px x 64 oc.
// W fragments read directly from global (L2-resident); LDS holds X only.
// DO NOT restructure the tap loop: r5/r6/r8/r9/r11/r13/r15 all regressed.
// The compiler's interleave of ds_read/MFMA is already optimal here.
// ---------------------------------------------------------------------------
template<int CIN, int MODE, bool SKIP>
__global__ __launch_bounds__(512)
void conv_mfma_kernel(const uint32_t* __restrict__ inPair,
                      const uint16_t* __restrict__ Wp,
                      const float* __restrict__ bias9,
                      const float* __restrict__ dmod,
                      const uint16_t* __restrict__ skp,
                      const float* __restrict__ skb,
                      float* __restrict__ skipOut,
                      uint32_t* __restrict__ outPair,
                      float* __restrict__ outF32,
                      float* __restrict__ statsH)
{
    __shared__ __align__(16) unsigned char LDS[41600];
    // X only: [4 rows][130 px], slot 80B, row stride 10400B.
    const int tid = threadIdx.x;
    const int lane = tid & 63, wv = tid >> 6;
    const int rw = wv >> 2, oq = wv & 3;

    int bid = blockIdx.x;
    bid = (bid & 7) * 256 + (bid >> 3);        // XCD-chunked bijective swizzle
    const int xh = bid & 1, yb = (bid >> 1) & 127, b = bid >> 8;
    const int y0 = yb*2, x0 = xh*128;

    union U8 { uint32_t u[4]; bf16x8 v; };

    f32x4 acc[8];
    f32x4 accS[SKIP ? 8 : 1];
    #pragma unroll
    for (int q = 0; q < 8; ++q) acc[q] = (f32x4){0.f, 0.f, 0.f, 0.f};
    if constexpr (SKIP) {
        #pragma unroll
        for (int q = 0; q < 8; ++q) accS[q] = (f32x4){0.f, 0.f, 0.f, 0.f};
    }

    const int NCH = CIN/16;
    for (int ic = 0; ic < NCH; ++ic) {
        // ---- stage X (only LDS use)
        for (int e = tid; e < 2080; e += 512) {
            int part = e & 3;
            int pr = e >> 2;
            int px = pr % 130, row = pr / 130;
            int yy = y0 - 1 + row, xx = x0 - 1 + px;
            uint4 v = {0u, 0u, 0u, 0u};
            if (yy >= 0 && yy < 256 && xx >= 0 && xx < 256)
                v = *reinterpret_cast<const uint4*>(
                    inPair + ((((size_t)b*NCH + ic)*256 + yy)*256 + xx)*16 + part*4);
            *reinterpret_cast<uint4*>(LDS + row*10400 + px*80 + part*16) = v;
        }
        __syncthreads();
        // ---- compute: 9 taps x 8 x-frags x 2 mfma; W from global (L2-hot)
        const uint16_t* wbase = Wp + ((size_t)b*NCH + ic)*18432
                              + oq*512 + (lane >> 4)*128 + (lane & 15)*8;
        #pragma unroll
        for (int tap = 0; tap < 9; ++tap) {
            const int dy1 = tap/3, dxm = tap % 3;
            uint4 wv4 = *reinterpret_cast<const uint4*>(wbase + tap*2048);
            U8 wa, wb;
            #pragma unroll
            for (int q = 0; q < 4; ++q) {
                uint32_t ww = (&wv4.x)[q];
                wa.u[q] = __builtin_amdgcn_perm(ww, ww, 0x01000100u);
                wb.u[q] = __builtin_amdgcn_perm(ww, ww, 0x03020302u);
            }
            U8 sa, sb;
            if constexpr (SKIP) {
                if (tap == 4) {
                    uint4 sfrag = *reinterpret_cast<const uint4*>(
                        skp + ic*2048 + oq*512 + (lane >> 4)*128 + (lane & 15)*8);
                    #pragma unroll
                    for (int q = 0; q < 4; ++q) {
                        uint32_t ww = (&sfrag.x)[q];
                        sa.u[q] = __builtin_amdgcn_perm(ww, ww, 0x01000100u);
                        sb.u[q] = __builtin_amdgcn_perm(ww, ww, 0x03020302u);
                    }
                }
            }
            const int rowbase = (rw + dy1)*10400 + (lane >> 4)*16 + ((lane & 15) + dxm)*80;
            #pragma unroll
            for (int xf = 0; xf < 8; ++xf) {
                bf16x8 bf = *reinterpret_cast<const bf16x8*>(LDS + rowbase + xf*1280);
                acc[xf] = __builtin_amdgcn_mfma_f32_16x16x32_bf16(wa.v, bf, acc[xf], 0, 0, 0);
                acc[xf] = __builtin_amdgcn_mfma_f32_16x16x32_bf16(wb.v, bf, acc[xf], 0, 0, 0);
                if constexpr (SKIP) {
                    if (tap == 4) {
                        accS[xf] = __builtin_amdgcn_mfma_f32_16x16x32_bf16(sa.v, bf, accS[xf], 0, 0, 0);
                        accS[xf] = __builtin_amdgcn_mfma_f32_16x16x32_bf16(sb.v, bf, accS[xf], 0, 0, 0);
                    }
                }
            }
        }
        __syncthreads();
    }

    // ---- epilogue
    const int y = y0 + rw;
    const int ry = (y == 0) ? 0 : ((y == 255) ? 2 : 1);
    float dv4[4], bmid[4], bl[4], br[4], skb4[4];
    #pragma unroll
    for (int r2 = 0; r2 < 4; ++r2) {
        int o = oq*16 + (lane >> 4)*4 + r2;
        dv4[r2] = dmod[b*64 + o];
        const float* bp = bias9 + ((size_t)(b*64 + o))*9 + ry*3;
        bmid[r2] = bp[1];
        bl[r2] = bmid[r2]; br[r2] = bmid[r2];
        if (x0 == 0   && (lane & 15) == 0)  bl[r2] = bp[0];
        if (x0 == 128 && (lane & 15) == 15) br[r2] = bp[2];
        if constexpr (SKIP) skb4[r2] = skb[o];
    }

    float s4[4] = {0.f,0.f,0.f,0.f}, q4[4] = {0.f,0.f,0.f,0.f};
    #pragma unroll
    for (int xf = 0; xf < 8; ++xf) {
        #pragma unroll
        for (int r2 = 0; r2 < 4; ++r2) {
            float bias = (xf == 0) ? bl[r2] : ((xf == 7) ? br[r2] : bmid[r2]);
            float v = (acc[xf][r2] + bias) * dv4[r2];
            v = leaky(v);
            acc[xf][r2] = v;
            if (MODE != 2) { s4[r2] += v; q4[r2] += v*v; }
        }
    }

    if constexpr (SKIP) {
        #pragma unroll
        for (int xf = 0; xf < 8; ++xf) {
            #pragma unroll
            for (int r2 = 0; r2 < 4; ++r2) {
                int o = oq*16 + (lane >> 4)*4 + r2;
                size_t addr = ((size_t)(b*64 + o))*65536 + (size_t)y*256 + x0 + xf*16 + (lane & 15);
                skipOut[addr] = accS[xf][r2] + skb4[r2];
            }
        }
    }

    if constexpr (MODE == 2) {
        #pragma unroll
        for (int xf = 0; xf < 8; ++xf) {
            #pragma unroll
            for (int r2 = 0; r2 < 4; ++r2) {
                int o = oq*16 + (lane >> 4)*4 + r2;
                size_t addr = ((size_t)(b*64 + o))*65536 + (size_t)y*256 + x0 + xf*16 + (lane & 15);
                float v = acc[xf][r2] + outF32[addr];
                outF32[addr] = v;
                s4[r2] += v; q4[r2] += v*v;
            }
        }
    }

    // stats reduce: 16 lanes share the same o's
    #pragma unroll
    for (int r2 = 0; r2 < 4; ++r2) {
        #pragma unroll
        for (int w = 1; w < 16; w <<= 1) {
            s4[r2] += __shfl_xor(s4[r2], w);
            q4[r2] += __shfl_xor(q4[r2], w);
        }
    }
    if ((lane & 15) == 0) {
        #pragma unroll
        for (int r2 = 0; r2 < 4; ++r2) {
            int o = oq*16 + (lane >> 4)*4 + r2;
            atomicAdd(&statsH[(b*64 + o)*2],     s4[r2]);
            atomicAdd(&statsH[(b*64 + o)*2 + 1], q4[r2]);
        }
    }

    if constexpr (MODE != 2) {
        // direct coalesced pair store (no LDS, no barriers)
        uint32_t* outb = outPair + ((((size_t)b*4 + oq)*256 + y)*256 + x0)*16 + (lane >> 4)*4;
        #pragma unroll
        for (int xf = 0; xf < 8; ++xf) {
            int px = xf*16 + (lane & 15);
            uint4 pk4;
            pk4.x = split_pack(acc[xf][0]);
            pk4.y = split_pack(acc[xf][1]);
            pk4.z = split_pack(acc[xf][2]);
            pk4.w = split_pack(acc[xf][3]);
            *reinterpret_cast<uint4*>(outb + (size_t)px*16) = pk4;
        }
    }
}

// ---------------------------------------------------------------------------
// RGB 1x1 modconv; instance-norm stats derived from fused sums.
// ---------------------------------------------------------------------------
__global__ __launch_bounds__(256)
void rgb_kernel(const float* __restrict__ h, const float* __restrict__ wr,
                const float* __restrict__ sty, const float* __restrict__ sums,
                float* __restrict__ rgb)
{
    __shared__ float A[64], Bc[64];
    __shared__ float wl[192];
    int bid = blockIdx.x;
    int b = bid >> 7;
    int px0 = (bid & 127) * 512;
    int tid = threadIdx.x;
    if (tid < 64) {
        float smv = sty[b*128 + tid];
        float av  = sty[1024 + b*128 + tid];
        float bv  = sty[2048 + b*128 + tid];
        float s0 = sums[(b*64 + tid)*2], s1 = sums[(b*64 + tid)*2 + 1];
        float m = s0 * (1.f/65536.f);
        float var = s1 * (1.f/65536.f) - m*m;
        float r = rsqrtf((var > 0.f ? var : 0.f) + 1e-5f);
        A[tid]  = smv * av * r;
        Bc[tid] = smv * (bv - av*m*r);
    }
    if (tid < 192) wl[tid] = wr[tid];
    __syncthreads();
    int pix = px0 + tid*2;
    const float* hp = h + (size_t)b*64*65536 + pix;
    float a0[3] = {0,0,0}, a1[3] = {0,0,0};
    for (int i = 0; i < 64; ++i) {
        float2 v = *reinterpret_cast<const float2*>(hp + (size_t)i*65536);
        float xi0 = fmaf(A[i], v.x, Bc[i]);
        float xi1 = fmaf(A[i], v.y, Bc[i]);
        #pragma unroll
        for (int o = 0; o < 3; ++o) {
            float wv = wl[o*64 + i];
            a0[o] = fmaf(wv, xi0, a0[o]);
            a1[o] = fmaf(wv, xi1, a1[o]);
        }
    }
    float* rp = rgb + (size_t)b*3*65536 + pix;
    #pragma unroll
    for (int o = 0; o < 3; ++o)
        *reinterpret_cast<float2*>(rp + (size_t)o*65536) = make_float2(a0[o], a1[o]);
}

// ---------------------------------------------------------------------------
extern "C" void kernel_launch(void* const* d_in, const int* in_sizes, int n_in,
                              void* d_out, int out_size, void* d_ws, size_t ws_size,
                              hipStream_t stream)
{
    const float* x     = (const float*)d_in[0];
    const float* w     = (const float*)d_in[1];
    const float* w1    = (const float*)d_in[2];
    const float* sc1   = (const float*)d_in[3];
    const float* m1_w  = (const float*)d_in[4];
    const float* m1_b  = (const float*)d_in[5];
    const float* ln1_g = (const float*)d_in[6];
    const float* ln1_b = (const float*)d_in[7];
    const float* a1_sw = (const float*)d_in[8];
    const float* a1_sb = (const float*)d_in[9];
    const float* a1_bw = (const float*)d_in[10];
    const float* a1_bb = (const float*)d_in[11];
    const float* w25   = (const float*)d_in[12];
    const float* sc25  = (const float*)d_in[13];
    const float* m25_w = (const float*)d_in[14];
    const float* m25_b = (const float*)d_in[15];
    const float* ln25_g= (const float*)d_in[16];
    const float* ln25_b= (const float*)d_in[17];
    const float* a25_sw= (const float*)d_in[18];
    const float* a25_sb= (const float*)d_in[19];
    const float* a25_bw= (const float*)d_in[20];
    const float* a25_bb= (const float*)d_in[21];
    const float* wr    = (const float*)d_in[22];
    const float* scr   = (const float*)d_in[23];
    const float* mr_w  = (const float*)d_in[24];
    const float* mr_b  = (const float*)d_in[25];
    const float* lnr_g = (const float*)d_in[26];
    const float* lnr_b = (const float*)d_in[27];
    const float* ar_sw = (const float*)d_in[28];
    const float* ar_sb = (const float*)d_in[29];
    const float* ar_bw = (const float*)d_in[30];
    const float* ar_bb = (const float*)d_in[31];
    const float* sk_w  = (const float*)d_in[32];
    const float* sk_b  = (const float*)d_in[33];

    float* outp    = (float*)d_out;
    float* h_out   = outp;                        // [8,64,256,256] f32
    float* rgb_out = outp + (size_t)33554432;     // [8,3,256,256]  f32

    uint8_t* ws = (uint8_t*)d_ws;
    uint32_t*  Upair  = (uint32_t*)(ws + 0);
    uint32_t*  hpB    = (uint32_t*)(ws + 0);
    uint32_t*  hpA    = (uint32_t*)(ws + 268435456ull);
    uint16_t*  WpBase = (uint16_t*)(ws + 402653184ull);
    float*     sty    = (float*)(ws + 409731072ull);
    float*     dmod   = (float*)(ws + 409804800ull);
    float*     stats  = (float*)(ws + 409815040ull);
    float*     bias9  = (float*)(ws + 409843712ull);
    uint16_t*  skp    = (uint16_t*)(ws + 409935872ull);

    float* sumsU = stats;
    float* st1   = stats + 2048;
    float* st2   = stats + 3072;
    float* st3   = stats + 4096;
    float* st4   = stats + 5120;
    float* st5   = stats + 6144;

    uint16_t* Wp1 = WpBase;
    uint16_t* Wp2 = WpBase + 1179648;
    uint16_t* Wp3 = Wp2 + 589824;
    uint16_t* Wp4 = Wp3 + 589824;
    uint16_t* Wp5 = Wp4 + 589824;

    hipMemsetAsync(stats, 0, 28672, stream);

    // 1. styles: single merged launch (6 layers x 8 batches concurrent)
    style_all_kernel<<<48,128,0,stream>>>(w,
        m1_w, m1_b, ln1_g, ln1_b, a1_sw, a1_sb, a1_bw, a1_bb, sc1,
        m25_w, m25_b, ln25_g, ln25_b, a25_sw, a25_sb, a25_bw, a25_bb, sc25,
        mr_w, mr_b, lnr_g, lnr_b, ar_sw, ar_sb, ar_bw, ar_bb, scr,
        sty);

    // 2. skip-weight pack (demod fused into packw)
    packskip_kernel<<<32,256,0,stream>>>(sk_w, skp);

    // 3. upsample -> pair tensor + sums
    upsample_pack_kernel<<<2048,256,0,stream>>>(x, Upair, sumsU);

    // 4. conv1 (128->64) with fused skip -> hpA pairs + h_out (skip f32)
    packw_kernel<128><<<512,128,0,stream>>>(w1, sty, sumsU, Wp1, bias9, dmod);
    conv_mfma_kernel<128,1,true><<<2048,512,0,stream>>>(Upair, Wp1, bias9, dmod,
                                                        skp, sk_b, h_out,
                                                        hpA, nullptr, st1);
    // 5. conv2..conv4
    packw_kernel<64><<<512,64,0,stream>>>(w25, sty + 3072, st1, Wp2, bias9 + 4608, dmod + 512);
    conv_mfma_kernel<64,1,false><<<2048,512,0,stream>>>(hpA, Wp2, bias9 + 4608, dmod + 512,
                                                        nullptr, nullptr, nullptr,
                                                        hpB, nullptr, st2);
    packw_kernel<64><<<512,64,0,stream>>>(w25 + 36864, sty + 2*3072, st2, Wp3, bias9 + 2*4608, dmod + 2*512);
    conv_mfma_kernel<64,1,false><<<2048,512,0,stream>>>(hpB, Wp3, bias9 + 2*4608, dmod + 2*512,
                                                        nullptr, nullptr, nullptr,
                                                        hpA, nullptr, st3);
    packw_kernel<64><<<512,64,0,stream>>>(w25 + 2*36864, sty + 3*3072, st3, Wp4, bias9 + 3*4608, dmod + 3*512);
    conv_mfma_kernel<64,1,false><<<2048,512,0,stream>>>(hpA, Wp4, bias9 + 3*4608, dmod + 3*512,
                                                        nullptr, nullptr, nullptr,
                                                        hpB, nullptr, st4);
    // 6. conv5 + skip add -> d_out.h (f32), h stats fused
    packw_kernel<64><<<512,64,0,stream>>>(w25 + 3*36864, sty + 4*3072, st4, Wp5, bias9 + 4*4608, dmod + 4*512);
    conv_mfma_kernel<64,2,false><<<2048,512,0,stream>>>(hpB, Wp5, bias9 + 4*4608, dmod + 4*512,
                                                        nullptr, nullptr, nullptr,
                                                        nullptr, h_out, st5);

    // 7. rgb head
    rgb_kernel<<<1024,256,0,stream>>>(h_out, wr, sty + 5*3072, st5, rgb_out);
}